// Round 5
// baseline (940.007 us; speedup 1.0000x reference)
//
#include <hip/hip_runtime.h>

// ESN reservoir, B=256, T=4096, D=8, U=64, leaky=1.0.
// Single fused kernel: one wave per sequence; lane u owns state[u].
//
// INVARIANT 1 (round-2): every in-loop load must be on vmcnt, never
// lgkmcnt. Wave-uniform projection loads scalarize to s_load (SMEM),
// which shares lgkmcnt with ds_bpermute -> conservative lgkmcnt(0)
// couples the HBM prefetch into the serial chain (+255 us). Fix: opaque
// VGPR zero (inline asm) added to the index -> global_load, vmcnt.
//
// INVARIANT 2 (round-4): ONE wave per CU -> the static schedule IS the
// wall time. All off-chain work must issue between the bpermute issues
// and the lgkmcnt wait (the ~120-200 cy DS-crossbar shadow).
//
// Round-5 changes:
//   - r-exchange: lanes exchange r = 1/(exp2(acc)+1) instead of
//     s = 1-2r. Consumers use coeffs -2*C*w_j; the constant sum
//     Sum(C*w_j) folds into the projection bias (zero step cost).
//     Removes the final fma from the serial chain; the stored value
//     (1-2r) moves fully off-chain.
//   - deferred store: step t's output store issues in step t+1's shadow
//     region (under DS latency), not on the chain tail. First store
//     targets workspace (or this block's last slot if no ws); epilogue
//     flushes the final step.
//   - sched_barrier(0) pins per-step regions: [bpermutes][shadow: proj +
//     deferred store][chain: reduce + exp2 + rcp]. Ping-pong group
//     buffers (xa/xb) kill the 8 per-group register copies.

constexpr int T_LEN = 4096;
constexpr int B_N   = 256;
constexpr int D_IN  = 8;
constexpr int U_N   = 64;
constexpr int MAXN  = 12;           // max nnz per W_rec column supported
constexpr int GS    = 8;            // timesteps per group (prefetch granule)
constexpr int NG    = T_LEN / GS;   // 512
constexpr float CSC = 2.885390081777927f;  // 2*log2(e)

// Project one timestep: v = C*(x . w) + bu. bu carries C*b + Sum(C*w_rec).
// x must be formally divergent (vzero) -> global_load, vmcnt.
__device__ __forceinline__ float project8(const float* __restrict__ x,
                                          const float (&w)[D_IN], float bu) {
    const float4* ip = (const float4*)x;
    float4 a = ip[0], c = ip[1];
    float v = bu;
    v = fmaf(a.x, w[0], v); v = fmaf(a.y, w[1], v);
    v = fmaf(a.z, w[2], v); v = fmaf(a.w, w[3], v);
    v = fmaf(c.x, w[4], v); v = fmaf(c.y, w[5], v);
    v = fmaf(c.z, w[6], v); v = fmaf(c.w, w[7], v);
    return v;
}

template<int NS>
__device__ __forceinline__ void group_body(int g,
                                           const float* __restrict__ xin,
                                           float* __restrict__ p,
                                           float (&xc)[GS], float (&xn)[GS],
                                           float& r_state, float*& pa,
                                           const float (&w)[D_IN], float bu,
                                           const int (&rsb)[MAXN],
                                           const float (&rwm2)[MAXN],
                                           int vzero) {
    const float* src = xin + (size_t)((g + 1 < NG) ? g + 1 : g) * (GS * D_IN)
                     + vzero;
    float* ps = p + (size_t)g * (GS * U_N);
#pragma unroll
    for (int s = 0; s < GS; ++s) {
        const int st = __float_as_int(r_state);
        // region 1: issue ALL cross-lane pulls back-to-back
        float t[NS];
#pragma unroll
        for (int j = 0; j < NS; ++j)
            t[j] = __int_as_float(__builtin_amdgcn_ds_bpermute(rsb[j], st));
        __builtin_amdgcn_sched_barrier(0);
        // region 2 (DS-latency shadow): next-group projection + the
        // PREVIOUS step's output store (s_{t-1} = 1 - 2*r_{t-1}).
        xn[s] = project8(src + s * D_IN, w, bu);
        *pa = fmaf(-2.f, r_state, 1.f);
        pa = ps + s * U_N;
        __builtin_amdgcn_sched_barrier(0);
        // region 3 (chain): reduce -> exp2 -> rcp
        float A  = fmaf(rwm2[0], t[0], xc[s]);
        float Bv = rwm2[1] * t[1];
#pragma unroll
        for (int j = 2; j + 1 < NS; j += 2) {
            A  = fmaf(rwm2[j],     t[j],     A);
            Bv = fmaf(rwm2[j + 1], t[j + 1], Bv);
        }
        float acc = A + Bv;
        float e   = __builtin_amdgcn_exp2f(acc);
        r_state   = __builtin_amdgcn_rcpf(e + 1.f);
    }
}

template<int NS>
__device__ __forceinline__ void run_scan(const float* __restrict__ xin,
                                         float* __restrict__ p,
                                         float* __restrict__ dummy,
                                         const float (&w)[D_IN], float bu,
                                         const int (&rsb)[MAXN],
                                         const float (&rwm2)[MAXN],
                                         int vzero) {
    static_assert(NS >= 4 && (NS % 2) == 0, "NS even, >=4");
    float xa[GS], xb[GS];

    // prologue: project group 0 (divergent addr -> vmcnt)
#pragma unroll
    for (int s = 0; s < GS; ++s)
        xa[s] = project8(xin + s * D_IN + vzero, w, bu);

    float r_state = 0.5f;        // s = 1-2r = 0  (zero initial state)
    float* pa = dummy;           // first deferred store is a throwaway

    for (int g = 0; g < NG; g += 2) {
        group_body<NS>(g,     xin, p, xa, xb, r_state, pa, w, bu, rsb, rwm2, vzero);
        group_body<NS>(g + 1, xin, p, xb, xa, r_state, pa, w, bu, rsb, rwm2, vzero);
    }
    // epilogue: flush the final step's output
    *pa = fmaf(-2.f, r_state, 1.f);
}

__global__ __launch_bounds__(64, 1)
void esn_scan_fused(const float* __restrict__ inputs,  // [B,T,D]
                    const float* __restrict__ W_in,    // [D,U]
                    const float* __restrict__ bias,    // [U]
                    const float* __restrict__ W_rec,   // [U,U]
                    float* __restrict__ out,           // [B,T,U]
                    float* __restrict__ ws)            // dummy-store target or null
{
    const int b = blockIdx.x;
    const int u = threadIdx.x;

    // opaque zero in a VGPR: defeats uniform-address scalarization (SMEM)
    // for the in-loop projection loads. See INVARIANT 1.
    int vzero;
    asm volatile("v_mov_b32 %0, 0" : "=v"(vzero));

    // per-lane input-projection column, pre-scaled by C
    float w[D_IN];
#pragma unroll
    for (int d = 0; d < D_IN; ++d) w[d] = W_in[d * U_N + u] * CSC;

    // compress column u of W_rec; coeffs are -2*C*w_j (r-exchange);
    // the constant Sum(C*w_j) folds into the projection bias.
    int rsb[MAXN]; float rwm2[MAXN];
#pragma unroll
    for (int j = 0; j < MAXN; ++j) { rsb[j] = 0; rwm2[j] = 0.f; }
    int n = 0; float swsum = 0.f;
    for (int k = 0; k < U_N; ++k) {
        float wv = W_rec[k * U_N + u];
        if (wv != 0.f && n < MAXN) {
            rsb[n] = k << 2;
            rwm2[n] = -2.f * wv * CSC;
            swsum += wv * CSC;
            ++n;
        }
    }
    const float bu = bias[u] * CSC + swsum;

    // wave-max nnz -> pick variant ONCE (branch-free inner loop)
    int M = n;
#pragma unroll
    for (int off = 32; off > 0; off >>= 1) {
        int o = __shfl_xor(M, off, 64);
        M = (o > M) ? o : M;
    }
    const int Mu = __builtin_amdgcn_readfirstlane(M);

    const float* xin = inputs + (size_t)b * (T_LEN * D_IN);
    float* p = out + (size_t)b * ((size_t)T_LEN * U_N) + u;
    // dummy-store target: workspace if present, else this block's last
    // slot (its throwaway 0-write is overwritten ~450us later by the
    // epilogue -> physically ordered, same lane, same address).
    float* dummy = ws ? (ws + u) : (p + (size_t)(T_LEN - 1) * U_N);

    if      (Mu <= 4)  run_scan<4 >(xin, p, dummy, w, bu, rsb, rwm2, vzero);
    else if (Mu <= 6)  run_scan<6 >(xin, p, dummy, w, bu, rsb, rwm2, vzero);
    else if (Mu <= 8)  run_scan<8 >(xin, p, dummy, w, bu, rsb, rwm2, vzero);
    else if (Mu <= 10) run_scan<10>(xin, p, dummy, w, bu, rsb, rwm2, vzero);
    else               run_scan<12>(xin, p, dummy, w, bu, rsb, rwm2, vzero);
}

extern "C" void kernel_launch(void* const* d_in, const int* in_sizes, int n_in,
                              void* d_out, int out_size, void* d_ws, size_t ws_size,
                              hipStream_t stream) {
    const float* inputs = (const float*)d_in[0];
    const float* W_in   = (const float*)d_in[1];
    const float* bias   = (const float*)d_in[2];
    const float* W_rec  = (const float*)d_in[3];
    float* out = (float*)d_out;
    float* ws  = (ws_size >= U_N * sizeof(float)) ? (float*)d_ws : nullptr;

    esn_scan_fused<<<dim3(B_N), dim3(U_N), 0, stream>>>(inputs, W_in, bias, W_rec,
                                                        out, ws);
}